// Round 1
// baseline (336.139 us; speedup 1.0000x reference)
//
#include <hip/hip_runtime.h>
#include <hip/hip_bf16.h>

using bf16x8 = __attribute__((ext_vector_type(8))) short;
using f32x4  = __attribute__((ext_vector_type(4))) float;

static constexpr int B_ = 2, S_ = 2048, D_ = 1024, H_ = 16, HD_ = 64;
static constexpr int BS_ = B_ * S_;                  // 4096 rows
static constexpr float CP_ = 0.18033688011112042f;   // log2(e)/sqrt(64)

// ---------- helpers ----------
__device__ __forceinline__ unsigned short bfbits(float x) {
    unsigned u = __builtin_bit_cast(unsigned, x);
    unsigned r = (u + 0x7fffu + ((u >> 16) & 1u)) >> 16;   // RNE
    return (unsigned short)r;
}
__device__ __forceinline__ short bfs(float x) { return (short)bfbits(x); }
__device__ __forceinline__ unsigned pack2(float a, float b) {
    return (unsigned)bfbits(a) | ((unsigned)bfbits(b) << 16);
}

// ---------- cast tokens f32 -> bf16 ----------
__global__ void cast_f32_bf16_kernel(const float* __restrict__ in,
                                     short* __restrict__ out, int n8) {
    int i = blockIdx.x * blockDim.x + threadIdx.x;
    if (i >= n8) return;
    const float4* p = (const float4*)in + (size_t)i * 2;
    float4 a = p[0], b = p[1];
    short tmp[8] = { bfs(a.x), bfs(a.y), bfs(a.z), bfs(a.w),
                     bfs(b.x), bfs(b.y), bfs(b.z), bfs(b.w) };
    *(int4*)(out + (size_t)i * 8) = *(int4*)tmp;
}

// ---------- transpose+cast weight: in [R][C] f32 -> out [C][R] bf16 ----------
__global__ void transpose_cast_f32_kernel(const float* __restrict__ in,
                                          short* __restrict__ out, int R, int C) {
    __shared__ short tile[64][65];
    int t = threadIdx.x;
    int r0 = blockIdx.y * 64, c0 = blockIdx.x * 64;
    int lr = t >> 2, lc0 = (t & 3) * 16;
    const float4* src = (const float4*)(in + (size_t)(r0 + lr) * C + c0 + lc0);
#pragma unroll
    for (int v = 0; v < 4; v++) {
        float4 f = src[v];
        tile[lr][lc0 + v * 4 + 0] = bfs(f.x);
        tile[lr][lc0 + v * 4 + 1] = bfs(f.y);
        tile[lr][lc0 + v * 4 + 2] = bfs(f.z);
        tile[lr][lc0 + v * 4 + 3] = bfs(f.w);
    }
    __syncthreads();
    int oc = t >> 2, os0 = (t & 3) * 16;
    short tmp[16];
#pragma unroll
    for (int j = 0; j < 16; j++) tmp[j] = tile[os0 + j][oc];
    short* dst = out + (size_t)(c0 + oc) * R + r0 + os0;
    *(int4*)(dst) = *(int4*)(tmp);
    *(int4*)(dst + 8) = *(int4*)(tmp + 8);
}

// ---------- transpose V (bf16): [B*S][D] head-cols -> Vt[b][h][64][S] ----------
__global__ void transpose_v_kernel(const short* __restrict__ V,
                                   short* __restrict__ Vt) {
    __shared__ short tile[64][65];
    int t = threadIdx.x;
    int sblk = blockIdx.x * 64;
    int h = blockIdx.y, b = blockIdx.z;
    int lr = t >> 2, lc0 = (t & 3) * 16;
    const short* src = V + (size_t)(b * S_ + sblk + lr) * D_ + h * HD_ + lc0;
    short tin[16];
    *(int4*)(tin) = *(const int4*)(src);
    *(int4*)(tin + 8) = *(const int4*)(src + 8);
#pragma unroll
    for (int j = 0; j < 16; j++) tile[lr][lc0 + j] = tin[j];
    __syncthreads();
    int od = t >> 2, os0 = (t & 3) * 16;
    short tmp[16];
#pragma unroll
    for (int j = 0; j < 16; j++) tmp[j] = tile[os0 + j][od];
    short* dst = Vt + ((size_t)(b * H_ + h) * HD_ + od) * S_ + sblk + os0;
    *(int4*)(dst) = *(int4*)(tmp);
    *(int4*)(dst + 8) = *(int4*)(tmp + 8);
}

// ---------- bf16 GEMM: C[M][N] = A[M][K] * BT[N][K]^T + bias ----------
template <int OUT_F32>
__global__ __launch_bounds__(256, 2)
void gemm_bt_kernel(const short* __restrict__ A, const short* __restrict__ BT,
                    const float* __restrict__ bias, void* __restrict__ Cout,
                    int M, int N, int K) {
    __shared__ __align__(16) short As[128 * 32];
    __shared__ __align__(16) short Bs[128 * 32];
    int t = threadIdx.x;
    int w = t >> 6, l = t & 63;
    int lq = l & 15, g = l >> 4;
    int rowBase = blockIdx.y * 128, colBase = blockIdx.x * 128;
    int wrow = (w >> 1) * 64, wcol = (w & 1) * 64;
    f32x4 acc[4][4] = {};
    int c0 = t, c1 = t + 256;
    const short* a0 = A + (size_t)(rowBase + (c0 >> 2)) * K + (c0 & 3) * 8;
    const short* a1 = A + (size_t)(rowBase + (c1 >> 2)) * K + (c1 & 3) * 8;
    const short* b0 = BT + (size_t)(colBase + (c0 >> 2)) * K + (c0 & 3) * 8;
    const short* b1 = BT + (size_t)(colBase + (c1 >> 2)) * K + (c1 & 3) * 8;
    for (int kt = 0; kt < K; kt += 32) {
        __syncthreads();
        *(int4*)(&As[c0 * 8]) = *(const int4*)(a0 + kt);
        *(int4*)(&As[c1 * 8]) = *(const int4*)(a1 + kt);
        *(int4*)(&Bs[c0 * 8]) = *(const int4*)(b0 + kt);
        *(int4*)(&Bs[c1 * 8]) = *(const int4*)(b1 + kt);
        __syncthreads();
        bf16x8 af[4], bfr[4];
#pragma unroll
        for (int mi = 0; mi < 4; mi++)
            af[mi] = *(const bf16x8*)(&As[(wrow + mi * 16 + lq) * 32 + 8 * g]);
#pragma unroll
        for (int ni = 0; ni < 4; ni++)
            bfr[ni] = *(const bf16x8*)(&Bs[(wcol + ni * 16 + lq) * 32 + 8 * g]);
#pragma unroll
        for (int mi = 0; mi < 4; mi++)
#pragma unroll
            for (int ni = 0; ni < 4; ni++)
                acc[mi][ni] = __builtin_amdgcn_mfma_f32_16x16x32_bf16(
                    af[mi], bfr[ni], acc[mi][ni], 0, 0, 0);
    }
#pragma unroll
    for (int mi = 0; mi < 4; mi++)
#pragma unroll
        for (int ni = 0; ni < 4; ni++) {
            int col = colBase + wcol + ni * 16 + lq;
            float bcol = bias[col];
#pragma unroll
            for (int r = 0; r < 4; r++) {
                int row = rowBase + wrow + mi * 16 + 4 * g + r;
                float v = acc[mi][ni][r] + bcol;
                if (OUT_F32)
                    ((float*)Cout)[(size_t)row * N + col] = v;
                else
                    ((short*)Cout)[(size_t)row * N + col] = bfs(v);
            }
        }
}

// ---------- fused two-branch attention ----------
// Per wave: 32 q-rows of one head. Swapped QK^T: ST = mfma(K_tile, Q_tile)
// puts P[q][key] in A-fragment layout after a per-wave LDS bounce.
__global__ __launch_bounds__(256, 2)
void attn_kernel(const short* __restrict__ Q, const short* __restrict__ Kb,
                 const short* __restrict__ Vt, short* __restrict__ featNeg,
                 short* __restrict__ featPos) {
    __shared__ __align__(16) short P_lds[4 * 2 * 16 * 40];  // [wave][br][16 q][40 pad]
    int t = threadIdx.x;
    int w = t >> 6, l = t & 63;
    int lq = l & 15, g = l >> 4;
    int qtile = blockIdx.x;  // 0..15
    int h = blockIdx.y, b = blockIdx.z;
    int qb0 = qtile * 128 + w * 32;
    const short* Qh = Q + (size_t)(b * S_) * D_ + h * HD_;
    const short* Kh = Kb + (size_t)(b * S_) * D_ + h * HD_;
    const short* Vh = Vt + (size_t)(b * H_ + h) * HD_ * S_;

    bf16x8 qa[2][2];
#pragma unroll
    for (int qi = 0; qi < 2; qi++)
#pragma unroll
        for (int hf = 0; hf < 2; hf++)
            qa[qi][hf] = *(const bf16x8*)(Qh + (size_t)(qb0 + qi * 16 + lq) * D_ +
                                          hf * 32 + 8 * g);

    f32x4 acc[2][2][4] = {};
    float lsum[2][2] = {};
    unsigned pbase0 = (unsigned)((w * 2 + 0) * 16 + lq) * 40;
    unsigned pbase1 = (unsigned)((w * 2 + 1) * 16 + lq) * 40;

    for (int kt = 0; kt < S_; kt += 32) {
        bf16x8 ka[2][2];
#pragma unroll
        for (int T = 0; T < 2; T++)
#pragma unroll
            for (int hf = 0; hf < 2; hf++)
                ka[T][hf] = *(const bf16x8*)(Kh + (size_t)(kt + T * 16 + lq) * D_ +
                                             hf * 32 + 8 * g);
        bf16x8 vb[4];
#pragma unroll
        for (int n = 0; n < 4; n++)
            vb[n] = *(const bf16x8*)(Vh + (size_t)(n * 16 + lq) * S_ + kt + 8 * g);

#pragma unroll
        for (int qi = 0; qi < 2; qi++) {
            f32x4 st0 = {}, st1 = {};
            st0 = __builtin_amdgcn_mfma_f32_16x16x32_bf16(ka[0][0], qa[qi][0], st0, 0, 0, 0);
            st0 = __builtin_amdgcn_mfma_f32_16x16x32_bf16(ka[0][1], qa[qi][1], st0, 0, 0, 0);
            st1 = __builtin_amdgcn_mfma_f32_16x16x32_bf16(ka[1][0], qa[qi][0], st1, 0, 0, 0);
            st1 = __builtin_amdgcn_mfma_f32_16x16x32_bf16(ka[1][1], qa[qi][1], st1, 0, 0, 0);
#pragma unroll
            for (int br = 0; br < 2; br++) {
                float sg = (br == 0) ? -CP_ : CP_;
                float p0 = exp2f(st0[0] * sg), p1 = exp2f(st0[1] * sg);
                float p2 = exp2f(st0[2] * sg), p3 = exp2f(st0[3] * sg);
                float p4 = exp2f(st1[0] * sg), p5 = exp2f(st1[1] * sg);
                float p6 = exp2f(st1[2] * sg), p7 = exp2f(st1[3] * sg);
                lsum[qi][br] += (p0 + p1 + p2 + p3) + (p4 + p5 + p6 + p7);
                unsigned base = (br == 0) ? pbase0 : pbase1;
                *(unsigned*)(&P_lds[base + 4 * g]) = pack2(p0, p1);
                *(unsigned*)(&P_lds[base + 4 * g + 2]) = pack2(p2, p3);
                *(unsigned*)(&P_lds[base + 16 + 4 * g]) = pack2(p4, p5);
                *(unsigned*)(&P_lds[base + 16 + 4 * g + 2]) = pack2(p6, p7);
            }
#pragma unroll
            for (int br = 0; br < 2; br++) {
                unsigned base = (br == 0) ? pbase0 : pbase1;
                bf16x8 pa = *(const bf16x8*)(&P_lds[base + 8 * g]);
#pragma unroll
                for (int n = 0; n < 4; n++)
                    acc[qi][br][n] = __builtin_amdgcn_mfma_f32_16x16x32_bf16(
                        pa, vb[n], acc[qi][br][n], 0, 0, 0);
            }
        }
    }

#pragma unroll
    for (int qi = 0; qi < 2; qi++)
#pragma unroll
        for (int br = 0; br < 2; br++) {
            float ls = lsum[qi][br];
            ls += __shfl_xor(ls, 16);
            ls += __shfl_xor(ls, 32);
            float inv = 1.0f / ls;
            short* dst = (br == 0) ? featNeg : featPos;
#pragma unroll
            for (int r = 0; r < 4; r++) {
                float invr = __shfl(inv, 4 * g + r);  // softmax state lives at lane lq==row
                int row = b * S_ + qb0 + qi * 16 + 4 * g + r;
#pragma unroll
                for (int n = 0; n < 4; n++) {
                    int col = h * HD_ + n * 16 + lq;
                    dst[(size_t)row * D_ + col] = bfs(acc[qi][br][n][r] * invr);
                }
            }
        }
}

// ---------- launch ----------
extern "C" void kernel_launch(void* const* d_in, const int* in_sizes, int n_in,
                              void* d_out, int out_size, void* d_ws, size_t ws_size,
                              hipStream_t stream) {
    const float* tokens = (const float*)d_in[0];
    const float* Wq = (const float*)d_in[1];
    const float* bq = (const float*)d_in[2];
    const float* Wk = (const float*)d_in[3];
    const float* bk = (const float*)d_in[4];
    const float* Wv = (const float*)d_in[5];
    const float* bv = (const float*)d_in[6];
    const float* Wo = (const float*)d_in[7];
    const float* bo = (const float*)d_in[8];

    const size_t MB = 1048576;
    if (ws_size < 64 * MB) return;  // need 64 MB scratch
    char* ws = (char*)d_ws;
    short* Xbf = (short*)(ws + 0 * MB);    // [4096][1024] bf16
    short* WqT = (short*)(ws + 8 * MB);    // [1024][1024] bf16 (transposed)
    short* WkT = (short*)(ws + 10 * MB);
    short* WvT = (short*)(ws + 12 * MB);
    short* WoT = (short*)(ws + 14 * MB);
    short* Qb  = (short*)(ws + 16 * MB);   // [4096][1024]
    short* Kbf = (short*)(ws + 24 * MB);
    short* Vb  = (short*)(ws + 32 * MB);
    short* Vt  = (short*)(ws + 40 * MB);   // [2][16][64][2048]
    short* featNeg = (short*)(ws + 48 * MB);  // [4096][1024]
    short* featPos = (short*)(ws + 56 * MB);  // contiguous after featNeg

    cast_f32_bf16_kernel<<<2048, 256, 0, stream>>>(tokens, Xbf, BS_ * D_ / 8);

    dim3 tg(16, 16);
    transpose_cast_f32_kernel<<<tg, 256, 0, stream>>>(Wq, WqT, D_, D_);
    transpose_cast_f32_kernel<<<tg, 256, 0, stream>>>(Wk, WkT, D_, D_);
    transpose_cast_f32_kernel<<<tg, 256, 0, stream>>>(Wv, WvT, D_, D_);
    transpose_cast_f32_kernel<<<tg, 256, 0, stream>>>(Wo, WoT, D_, D_);

    dim3 gq(D_ / 128, BS_ / 128);  // (8, 32)
    gemm_bt_kernel<0><<<gq, 256, 0, stream>>>(Xbf, WqT, bq, Qb, BS_, D_, D_);
    gemm_bt_kernel<0><<<gq, 256, 0, stream>>>(Xbf, WkT, bk, Kbf, BS_, D_, D_);
    gemm_bt_kernel<0><<<gq, 256, 0, stream>>>(Xbf, WvT, bv, Vb, BS_, D_, D_);

    transpose_v_kernel<<<dim3(S_ / 64, H_, B_), 256, 0, stream>>>(Vb, Vt);

    attn_kernel<<<dim3(S_ / 128, H_, B_), 256, 0, stream>>>(Qb, Kbf, Vt, featNeg, featPos);

    // final projection on both branches at once: [8192][1024] -> d_out f32
    gemm_bt_kernel<1><<<dim3(D_ / 128, 2 * BS_ / 128), 256, 0, stream>>>(
        featNeg, WoT, bo, d_out, 2 * BS_, D_, D_);
}